// Round 7
// baseline (93.042 us; speedup 1.0000x reference)
//
#include <hip/hip_runtime.h>
#include <hip/hip_bf16.h>

#define HIDDEN 512
#define SEQ 256

typedef float f32x4 __attribute__((ext_vector_type(4)));

// One wave = one h (W wave-uniform -> scalar loads). Lane = bl*8 + tp:
// 8 batches x 8 chunk-pairs. Each lane owns 128B of x/y (2 adjacent 16-chunks)
// -> one full cache line per lane, 8 loads in flight, W amortized 2x.
// Keep VGPR <= 64 (8 waves/SIMD): process chunk A fully, then chunk B
// (xr regs freed between; W s_loads re-hit scalar cache).
__device__ __forceinline__ float dot16(const f32x4& x0, const f32x4& x1,
                                       const f32x4& x2, const f32x4& x3,
                                       const f32x4& w0, const f32x4& w1,
                                       const f32x4& w2, const f32x4& w3) {
  float a;
  a = x0.x * w0.x;
  a = fmaf(x0.y, w0.y, a);
  a = fmaf(x0.z, w0.z, a);
  a = fmaf(x0.w, w0.w, a);
  a = fmaf(x1.x, w1.x, a);
  a = fmaf(x1.y, w1.y, a);
  a = fmaf(x1.z, w1.z, a);
  a = fmaf(x1.w, w1.w, a);
  a = fmaf(x2.x, w2.x, a);
  a = fmaf(x2.y, w2.y, a);
  a = fmaf(x2.z, w2.z, a);
  a = fmaf(x2.w, w2.w, a);
  a = fmaf(x3.x, w3.x, a);
  a = fmaf(x3.y, w3.y, a);
  a = fmaf(x3.z, w3.z, a);
  a = fmaf(x3.w, w3.w, a);
  return a;
}

__global__ __launch_bounds__(256) void LocalMixer_47579647705675_kernel(
    const float* __restrict__ x, const float* __restrict__ W,
    float* __restrict__ y) {
  const int tid  = threadIdx.x;
  const int wave = tid >> 6;
  const int lane = tid & 63;
  const int bl   = lane >> 3;  // batch within wave (8)
  const int tp   = lane & 7;   // chunk-pair within row (8)

  const int blk    = blockIdx.x;
  const int b_tile = blk >> 7;   // 32 tiles of 8 b
  const int h_tile = blk & 127;  // 128 tiles of 4 h
  const int b = b_tile * 8 + bl;
  int h = h_tile * 4 + wave;
  h = __builtin_amdgcn_readfirstlane(h);  // force SGPR base for W

  const f32x4* Wp = reinterpret_cast<const f32x4*>(W + (size_t)h * 256);

  const size_t base = ((size_t)b * HIDDEN + h) * SEQ + (size_t)tp * 32;

  // Issue all 8 x-loads up front (128B contiguous per lane).
  const f32x4* xp = reinterpret_cast<const f32x4*>(x + base);
  f32x4 xr[8];
#pragma unroll
  for (int j = 0; j < 8; ++j) xr[j] = xp[j];

  f32x4* yp = reinterpret_cast<f32x4*>(y + base);

  // Chunk A (floats 0..15), then chunk B (floats 16..31).
#pragma unroll
  for (int c = 0; c < 2; ++c) {
    f32x4 out[4];
#pragma unroll
    for (int oq = 0; oq < 4; ++oq) {
      float acc[4];
#pragma unroll
      for (int oi = 0; oi < 4; ++oi) {
        const int o = oq * 4 + oi;
        const f32x4 w0 = Wp[4 * o + 0];
        const f32x4 w1 = Wp[4 * o + 1];
        const f32x4 w2 = Wp[4 * o + 2];
        const f32x4 w3 = Wp[4 * o + 3];
        acc[oi] = dot16(xr[c * 4 + 0], xr[c * 4 + 1], xr[c * 4 + 2],
                        xr[c * 4 + 3], w0, w1, w2, w3);
      }
      out[oq] = (f32x4){acc[0], acc[1], acc[2], acc[3]};
    }
#pragma unroll
    for (int oq = 0; oq < 4; ++oq) yp[c * 4 + oq] = out[oq];
  }
}

extern "C" void kernel_launch(void* const* d_in, const int* in_sizes, int n_in,
                              void* d_out, int out_size, void* d_ws, size_t ws_size,
                              hipStream_t stream) {
  const float* x = (const float*)d_in[0];
  const float* W = (const float*)d_in[1];
  float* y = (float*)d_out;

  const int B = in_sizes[0] / (HIDDEN * SEQ);      // 256
  const int grid = (B / 8) * (HIDDEN / 4);         // 4096 blocks
  LocalMixer_47579647705675_kernel<<<grid, 256, 0, stream>>>(x, W, y);
}

// Round 8
// 69.590 us; speedup vs baseline: 1.3370x; 1.3370x over previous
//
#include <hip/hip_runtime.h>
#include <hip/hip_bf16.h>

#define HIDDEN 512
#define SEQ 256

typedef float f32x4 __attribute__((ext_vector_type(4)));

// R3 structure + depth-2 software pipeline.
// One wave = one h (W wave-uniform -> SGPR via scalar loads).
// Lane = bl*16 + t (4 batches x 16 chunks); each thread does TWO work items:
// (b, h, t) and (b+128, h, t). All 8 x-loads issued up front (2x the
// outstanding loads of R3), then compute+store each item with the proven
// back-to-back 4x16B store pattern (stores covering a line must be
// temporally dense -- R2/R7 write-allocate lesson).
__device__ __forceinline__ float dot16(const f32x4& x0, const f32x4& x1,
                                       const f32x4& x2, const f32x4& x3,
                                       const f32x4& w0, const f32x4& w1,
                                       const f32x4& w2, const f32x4& w3) {
  float a;
  a = x0.x * w0.x;
  a = fmaf(x0.y, w0.y, a);
  a = fmaf(x0.z, w0.z, a);
  a = fmaf(x0.w, w0.w, a);
  a = fmaf(x1.x, w1.x, a);
  a = fmaf(x1.y, w1.y, a);
  a = fmaf(x1.z, w1.z, a);
  a = fmaf(x1.w, w1.w, a);
  a = fmaf(x2.x, w2.x, a);
  a = fmaf(x2.y, w2.y, a);
  a = fmaf(x2.z, w2.z, a);
  a = fmaf(x2.w, w2.w, a);
  a = fmaf(x3.x, w3.x, a);
  a = fmaf(x3.y, w3.y, a);
  a = fmaf(x3.z, w3.z, a);
  a = fmaf(x3.w, w3.w, a);
  return a;
}

__global__ __launch_bounds__(256) void LocalMixer_47579647705675_kernel(
    const float* __restrict__ x, const float* __restrict__ W,
    float* __restrict__ y) {
  const int tid  = threadIdx.x;
  const int wave = tid >> 6;
  const int lane = tid & 63;
  const int bl   = lane >> 4;  // batch-sub within wave (4)
  const int t    = lane & 15;  // chunk within row (16)

  const int blk    = blockIdx.x;
  const int b_tile = blk >> 7;   // 32 tiles of 4 b (item1 adds +128 b)
  const int h_tile = blk & 127;  // 128 tiles of 4 h
  const int b = b_tile * 4 + bl;
  int h = h_tile * 4 + wave;
  h = __builtin_amdgcn_readfirstlane(h);  // force SGPR base for W

  const f32x4* Wp = reinterpret_cast<const f32x4*>(W + (size_t)h * 256);

  const size_t base0 = ((size_t)b * HIDDEN + h) * SEQ + (size_t)t * 16;
  const size_t base1 = base0 + (size_t)128 * HIDDEN * SEQ;  // b + 128

  // Issue all 8 x-loads up front (two items' worth of MLP).
  const f32x4* xp0 = reinterpret_cast<const f32x4*>(x + base0);
  const f32x4* xp1 = reinterpret_cast<const f32x4*>(x + base1);
  f32x4 xa0 = xp0[0], xa1 = xp0[1], xa2 = xp0[2], xa3 = xp0[3];
  f32x4 xb0 = xp1[0], xb1 = xp1[1], xb2 = xp1[2], xb3 = xp1[3];

  // Item 0
  {
    f32x4 out[4];
#pragma unroll
    for (int oq = 0; oq < 4; ++oq) {
      float acc[4];
#pragma unroll
      for (int oi = 0; oi < 4; ++oi) {
        const int o = oq * 4 + oi;
        acc[oi] = dot16(xa0, xa1, xa2, xa3, Wp[4 * o + 0], Wp[4 * o + 1],
                        Wp[4 * o + 2], Wp[4 * o + 3]);
      }
      out[oq] = (f32x4){acc[0], acc[1], acc[2], acc[3]};
    }
    f32x4* yp = reinterpret_cast<f32x4*>(y + base0);
#pragma unroll
    for (int oq = 0; oq < 4; ++oq) yp[oq] = out[oq];
  }

  // Item 1
  {
    f32x4 out[4];
#pragma unroll
    for (int oq = 0; oq < 4; ++oq) {
      float acc[4];
#pragma unroll
      for (int oi = 0; oi < 4; ++oi) {
        const int o = oq * 4 + oi;
        acc[oi] = dot16(xb0, xb1, xb2, xb3, Wp[4 * o + 0], Wp[4 * o + 1],
                        Wp[4 * o + 2], Wp[4 * o + 3]);
      }
      out[oq] = (f32x4){acc[0], acc[1], acc[2], acc[3]};
    }
    f32x4* yp = reinterpret_cast<f32x4*>(y + base1);
#pragma unroll
    for (int oq = 0; oq < 4; ++oq) yp[oq] = out[oq];
  }
}

extern "C" void kernel_launch(void* const* d_in, const int* in_sizes, int n_in,
                              void* d_out, int out_size, void* d_ws, size_t ws_size,
                              hipStream_t stream) {
  const float* x = (const float*)d_in[0];
  const float* W = (const float*)d_in[1];
  float* y = (float*)d_out;

  const int B = in_sizes[0] / (HIDDEN * SEQ);      // 256
  const int grid = (B / 8) * (HIDDEN / 4);         // 4096 blocks
  LocalMixer_47579647705675_kernel<<<grid, 256, 0, stream>>>(x, W, y);
}

// Round 9
// 46.210 us; speedup vs baseline: 2.0134x; 1.5059x over previous
//
#include <hip/hip_runtime.h>
#include <hip/hip_bf16.h>

#define HIDDEN 512
#define SEQ 256

typedef float f32x4 __attribute__((ext_vector_type(4)));

// Copy-granularity design. One wave = one h x 8 batches (an octet).
// Per row (1KB = 64 lanes x 16B): ONE fully-contiguous wave load, quad-local
// shfl_xor gather of the 16-float chunk, 64 FMAs vs per-lane W fragment,
// ONE fully-contiguous wave store. Every vmem instruction covers full 128B
// lines (R3's 32B/line-touch pattern is the hypothesized 8B/cy/CU cap).
// lane l: chunk c = l>>2, g-slice k = l&3 (floats 4l..4l+3 of the row).
// Wv[oi][m] = W[h, 4k+oi, 4(k^m)..+3]  (64 VGPRs, loaded once per wave).
// out[oi] = output (4k+oi) of chunk c -> store at float offset 4l+oi: the
// wave store is exactly the contiguous row.
__global__ __launch_bounds__(256) void LocalMixer_47579647705675_kernel(
    const float* __restrict__ x, const float* __restrict__ W,
    float* __restrict__ y) {
  const int tid  = threadIdx.x;
  const int wave = tid >> 6;
  const int lane = tid & 63;
  const int k    = lane & 3;

  const int wg  = blockIdx.x * 4 + wave;   // global wave id, 0..16383
  const int h   = wg & (HIDDEN - 1);
  const int oct = wg >> 9;                 // 0..31: batches oct*8 .. +7

  // Per-lane W fragment (16 x b128 loads, W row is L1/L2-hot).
  f32x4 Wv[4][4];
  {
    const float* Wh = W + (size_t)h * 256;
#pragma unroll
    for (int oi = 0; oi < 4; ++oi)
#pragma unroll
      for (int m = 0; m < 4; ++m)
        Wv[oi][m] = *reinterpret_cast<const f32x4*>(
            Wh + (4 * k + oi) * 16 + 4 * (k ^ m));
  }

  const size_t rowstride = (size_t)HIDDEN * SEQ;  // one batch step
  const size_t base = ((size_t)(oct * 8) * HIDDEN + h) * SEQ + lane * 4;
  const float* xp = x + base;
  float* yp = y + base;

  f32x4 xcur = *reinterpret_cast<const f32x4*>(xp);
#pragma unroll
  for (int r = 0; r < 8; ++r) {
    f32x4 xnext = xcur;
    if (r < 7)
      xnext = *reinterpret_cast<const f32x4*>(xp + (size_t)(r + 1) * rowstride);

    // Gather the other 3 g-slices of this quad's chunk.
    f32x4 xs1, xs2, xs3;
#pragma unroll
    for (int gi = 0; gi < 4; ++gi) {
      xs1[gi] = __shfl_xor(xcur[gi], 1);
      xs2[gi] = __shfl_xor(xcur[gi], 2);
      xs3[gi] = __shfl_xor(xcur[gi], 3);
    }

    f32x4 out;
#pragma unroll
    for (int oi = 0; oi < 4; ++oi) {
      float a;
      a = Wv[oi][0][0] * xcur[0];
      a = fmaf(Wv[oi][0][1], xcur[1], a);
      a = fmaf(Wv[oi][0][2], xcur[2], a);
      a = fmaf(Wv[oi][0][3], xcur[3], a);
      a = fmaf(Wv[oi][1][0], xs1[0], a);
      a = fmaf(Wv[oi][1][1], xs1[1], a);
      a = fmaf(Wv[oi][1][2], xs1[2], a);
      a = fmaf(Wv[oi][1][3], xs1[3], a);
      a = fmaf(Wv[oi][2][0], xs2[0], a);
      a = fmaf(Wv[oi][2][1], xs2[1], a);
      a = fmaf(Wv[oi][2][2], xs2[2], a);
      a = fmaf(Wv[oi][2][3], xs2[3], a);
      a = fmaf(Wv[oi][3][0], xs3[0], a);
      a = fmaf(Wv[oi][3][1], xs3[1], a);
      a = fmaf(Wv[oi][3][2], xs3[2], a);
      a = fmaf(Wv[oi][3][3], xs3[3], a);
      out[oi] = a;
    }

    *reinterpret_cast<f32x4*>(yp + (size_t)r * rowstride) = out;
    xcur = xnext;
  }
}

extern "C" void kernel_launch(void* const* d_in, const int* in_sizes, int n_in,
                              void* d_out, int out_size, void* d_ws, size_t ws_size,
                              hipStream_t stream) {
  const float* x = (const float*)d_in[0];
  const float* W = (const float*)d_in[1];
  float* y = (float*)d_out;

  const int B = in_sizes[0] / (HIDDEN * SEQ);        // 256
  const int grid = (B / 8) * HIDDEN / 4;             // 4096 blocks
  LocalMixer_47579647705675_kernel<<<grid, 256, 0, stream>>>(x, W, y);
}

// Round 10
// 44.953 us; speedup vs baseline: 2.0697x; 1.0280x over previous
//
#include <hip/hip_runtime.h>
#include <hip/hip_bf16.h>

#define HIDDEN 512
#define SEQ 256

typedef float f32x4 __attribute__((ext_vector_type(4)));

// R9 (copy-granularity, one wave = one h x 8 batches) with the quad-local
// shuffles moved from ds_swizzle (LDS pipe, lgkmcnt) to DPP quad_perm
// (1-cycle VALU). Masks 1,2,3 within quads: ctrl 0xB1 / 0x4E / 0x1B.
template <int CTRL>
__device__ __forceinline__ float qperm(float v) {
  int i = __builtin_bit_cast(int, v);
  i = __builtin_amdgcn_update_dpp(0, i, CTRL, 0xF, 0xF, true);
  return __builtin_bit_cast(float, i);
}

__global__ __launch_bounds__(256) void LocalMixer_47579647705675_kernel(
    const float* __restrict__ x, const float* __restrict__ W,
    float* __restrict__ y) {
  const int tid  = threadIdx.x;
  const int wave = tid >> 6;
  const int lane = tid & 63;
  const int k    = lane & 3;

  const int wg  = blockIdx.x * 4 + wave;   // global wave id, 0..16383
  const int h   = wg & (HIDDEN - 1);
  const int oct = wg >> 9;                 // 0..31: batches oct*8 .. +7

  // Per-lane W fragment (16 x b128 loads, W row is L1/L2-hot).
  f32x4 Wv[4][4];
  {
    const float* Wh = W + (size_t)h * 256;
#pragma unroll
    for (int oi = 0; oi < 4; ++oi)
#pragma unroll
      for (int m = 0; m < 4; ++m)
        Wv[oi][m] = *reinterpret_cast<const f32x4*>(
            Wh + (4 * k + oi) * 16 + 4 * (k ^ m));
  }

  const size_t rowstride = (size_t)HIDDEN * SEQ;  // one batch step
  const size_t base = ((size_t)(oct * 8) * HIDDEN + h) * SEQ + lane * 4;
  const float* xp = x + base;
  float* yp = y + base;

  f32x4 xcur = *reinterpret_cast<const f32x4*>(xp);
#pragma unroll
  for (int r = 0; r < 8; ++r) {
    f32x4 xnext = xcur;
    if (r < 7)
      xnext = *reinterpret_cast<const f32x4*>(xp + (size_t)(r + 1) * rowstride);

    // Gather the other 3 g-slices of this quad's chunk via DPP (VALU pipe).
    f32x4 xs1, xs2, xs3;
#pragma unroll
    for (int gi = 0; gi < 4; ++gi) {
      xs1[gi] = qperm<0xB1>(xcur[gi]);  // quad_perm [1,0,3,2]  (xor 1)
      xs2[gi] = qperm<0x4E>(xcur[gi]);  // quad_perm [2,3,0,1]  (xor 2)
      xs3[gi] = qperm<0x1B>(xcur[gi]);  // quad_perm [3,2,1,0]  (xor 3)
    }

    f32x4 out;
#pragma unroll
    for (int oi = 0; oi < 4; ++oi) {
      float a;
      a = Wv[oi][0][0] * xcur[0];
      a = fmaf(Wv[oi][0][1], xcur[1], a);
      a = fmaf(Wv[oi][0][2], xcur[2], a);
      a = fmaf(Wv[oi][0][3], xcur[3], a);
      a = fmaf(Wv[oi][1][0], xs1[0], a);
      a = fmaf(Wv[oi][1][1], xs1[1], a);
      a = fmaf(Wv[oi][1][2], xs1[2], a);
      a = fmaf(Wv[oi][1][3], xs1[3], a);
      a = fmaf(Wv[oi][2][0], xs2[0], a);
      a = fmaf(Wv[oi][2][1], xs2[1], a);
      a = fmaf(Wv[oi][2][2], xs2[2], a);
      a = fmaf(Wv[oi][2][3], xs2[3], a);
      a = fmaf(Wv[oi][3][0], xs3[0], a);
      a = fmaf(Wv[oi][3][1], xs3[1], a);
      a = fmaf(Wv[oi][3][2], xs3[2], a);
      a = fmaf(Wv[oi][3][3], xs3[3], a);
      out[oi] = a;
    }

    *reinterpret_cast<f32x4*>(yp + (size_t)r * rowstride) = out;
    xcur = xnext;
  }
}

extern "C" void kernel_launch(void* const* d_in, const int* in_sizes, int n_in,
                              void* d_out, int out_size, void* d_ws, size_t ws_size,
                              hipStream_t stream) {
  const float* x = (const float*)d_in[0];
  const float* W = (const float*)d_in[1];
  float* y = (float*)d_out;

  const int B = in_sizes[0] / (HIDDEN * SEQ);        // 256
  const int grid = (B / 8) * HIDDEN / 4;             // 4096 blocks
  LocalMixer_47579647705675_kernel<<<grid, 256, 0, stream>>>(x, W, y);
}